// Round 15
// baseline (378.329 us; speedup 1.0000x reference)
//
#include <hip/hip_runtime.h>
#include <hip/hip_bf16.h>

typedef __hip_bfloat16 bf16;
typedef float f32x4 __attribute__((ext_vector_type(4)));
typedef short bf16x8 __attribute__((ext_vector_type(8)));

static __device__ __forceinline__ void gload_lds16(const void* g, void* l) {
    __builtin_amdgcn_global_load_lds(
        (const __attribute__((address_space(1))) void*)g,
        (__attribute__((address_space(3))) void*)l, 16, 0, 0);
}

static __device__ __forceinline__ short bf16bits(float v) {
    bf16 tb = __float2bfloat16(v);
    return *reinterpret_cast<short*>(&tb);
}

static __device__ __forceinline__ float exp2_fast(float x) {
    float r;
    asm("v_exp_f32 %0, %1" : "=v"(r) : "v"(x));
    return r;
}

// V-row swizzle: groups {d, d+8, d+16, d+24} get disjoint bank slots.
static __device__ __forceinline__ int vswz(int d) {
    return ((d & 7) ^ ((d >> 3) << 1)) << 3;
}

// ---------------- fp32 -> bf16 conversion (vectorized) ----------------
__global__ __launch_bounds__(256) void cvt_x_kernel(const float4* __restrict__ x,
                                                    bf16* __restrict__ xb, int n4) {
    int i = blockIdx.x * 256 + threadIdx.x;
    const int stride = gridDim.x * 256;
    for (; i < n4; i += stride) {
        float4 v = x[i];
        alignas(8) bf16 tmp[4];
        tmp[0] = __float2bfloat16(v.x);
        tmp[1] = __float2bfloat16(v.y);
        tmp[2] = __float2bfloat16(v.z);
        tmp[3] = __float2bfloat16(v.w);
        *reinterpret_cast<uint2*>(xb + 4l * i) = *reinterpret_cast<uint2*>(tmp);
    }
}

// ---------------- build W_eff^T (fold LoRA), bf16 ----------------
__global__ __launch_bounds__(256) void build_wefft_kernel(
    const float* __restrict__ qkv_w, const float* __restrict__ qa,
    const float* __restrict__ qb, const float* __restrict__ va,
    const float* __restrict__ vb, bf16* __restrict__ wt) {
    int idx = blockIdx.x * 256 + threadIdx.x;  // 1152*384 total
    int ncol = idx / 384;
    int k = idx - ncol * 384;
    float v = qkv_w[k * 1152 + ncol];
    if (ncol < 384) {
        float s = 0.f;
#pragma unroll
        for (int j = 0; j < 16; ++j) s += qa[k * 16 + j] * qb[j * 384 + ncol];
        v += s;
    } else if (ncol >= 768) {
        int nc = ncol - 768;
        float s = 0.f;
#pragma unroll
        for (int j = 0; j < 16; ++j) s += va[k * 16 + j] * vb[j * 384 + nc];
        v += s;
    }
    wt[(long)ncol * 384 + k] = __float2bfloat16(v);
}

// ---------------- transpose proj_w, bf16 ----------------
__global__ __launch_bounds__(256) void build_projt_kernel(const float* __restrict__ pw,
                                                          bf16* __restrict__ pt) {
    int idx = blockIdx.x * 256 + threadIdx.x;  // 384*384 total
    int ncol = idx / 384;
    int k = idx - ncol * 384;
    pt[(long)ncol * 384 + k] = __float2bfloat16(pw[k * 384 + ncol]);
}

// ------- padded+prescaled bias: cbias[h][w][i*64+j], value*(log2 e) -------
// j>=49 -> -1e30 (exp2 -> 0); i in [49,64) pad rows -> 0 (rows discarded).
__global__ __launch_bounds__(256) void build_cbias_kernel(const float* __restrict__ rpb_table,
                                                          const float* __restrict__ mask,
                                                          float* __restrict__ cbias) {
    int idx = blockIdx.x * 256 + threadIdx.x;  // 12*64*64*64 = 12288*256
    int h = idx >> 18;
    int w = (idx >> 12) & 63;
    int ij = idx & 4095;
    int i = ij >> 6, j = ij & 63;
    float v;
    if (j < 49) {
        if (i < 49) {
            int yi = i / 7, xi = i - yi * 7;
            int yj = j / 7, xj = j - yj * 7;
            int rel = (yi - yj + 6) * 13 + (xi - xj + 6);
            v = (rpb_table[rel * 12 + h] + mask[w * 2401 + i * 49 + j]) * 1.4426950408889634f;
        } else {
            v = 0.f;
        }
    } else {
        v = -1e30f;
    }
    cbias[idx] = v;
}

// ---------------- GEMM (R5 known-good): C[M,N] = A[M,K] @ BT[N,K]^T + bias ----
template <bool OUT_BF16>
__global__ __launch_bounds__(256) void gemm_kernel(const bf16* __restrict__ A,
                                                   const bf16* __restrict__ BT,
                                                   const float* __restrict__ bias,
                                                   void* __restrict__ Cout,
                                                   int N, int K, int nxb, int nwg) {
    __shared__ short Al[128 * 64];
    __shared__ short Bl[128 * 64];
    const int t = threadIdx.x;
    const int lane = t & 63;
    const int wave = t >> 6;
    const int wr = wave >> 1;
    const int wc = wave & 1;
    const int g = lane >> 4, c = lane & 15;

    const int q8 = nwg >> 3;
    const int wgid = (blockIdx.x & 7) * q8 + (blockIdx.x >> 3);
    const int by = wgid / nxb;
    const int bx = wgid - by * nxb;
    const long rowBase = (long)by * 128;
    const long colBase = (long)bx * 128;

    f32x4 acc[4][4];
#pragma unroll
    for (int m = 0; m < 4; ++m)
#pragma unroll
        for (int n = 0; n < 4; ++n) acc[m][n] = (f32x4){0.f, 0.f, 0.f, 0.f};

    for (int k0 = 0; k0 < K; k0 += 64) {
        __syncthreads();
#pragma unroll
        for (int it = 0; it < 4; ++it) {
            int chunk = it * 256 + t;
            int row = chunk >> 3;
            int blk = lane & 7;
            gload_lds16(A + (size_t)(rowBase + row) * K + k0 + ((blk ^ (row & 7)) * 8),
                        &Al[(it * 256 + wave * 64) * 8]);
            gload_lds16(BT + (size_t)(colBase + row) * K + k0 + ((blk ^ (row & 7)) * 8),
                        &Bl[(it * 256 + wave * 64) * 8]);
        }
        asm volatile("s_waitcnt vmcnt(0)" ::: "memory");
        __syncthreads();

#pragma unroll
        for (int ks = 0; ks < 2; ++ks) {
            bf16x8 af[4], bfr[4];
#pragma unroll
            for (int m = 0; m < 4; ++m) {
                int row = wr * 64 + m * 16 + c;
                af[m] = *(const bf16x8*)&Al[row * 64 + (((ks * 4 + g) ^ (c & 7)) * 8)];
            }
#pragma unroll
            for (int n = 0; n < 4; ++n) {
                int row = wc * 64 + n * 16 + c;
                bfr[n] = *(const bf16x8*)&Bl[row * 64 + (((ks * 4 + g) ^ (c & 7)) * 8)];
            }
#pragma unroll
            for (int m = 0; m < 4; ++m)
#pragma unroll
                for (int n = 0; n < 4; ++n)
                    acc[m][n] = __builtin_amdgcn_mfma_f32_16x16x32_bf16(af[m], bfr[n],
                                                                        acc[m][n], 0, 0, 0);
        }
    }

    const int crow0 = wr * 64 + g * 4;
    const long ccol0 = colBase + wc * 64 + c;
#pragma unroll
    for (int m = 0; m < 4; ++m) {
#pragma unroll
        for (int n = 0; n < 4; ++n) {
            const long col = ccol0 + n * 16;
            const float bv = bias[col];
#pragma unroll
            for (int r = 0; r < 4; ++r) {
                const long row = rowBase + crow0 + m * 16 + r;
                float v = acc[m][n][r] + bv;
                if (OUT_BF16)
                    ((bf16*)Cout)[row * N + col] = __float2bfloat16(v);
                else
                    ((float*)Cout)[row * N + col] = v;
            }
        }
    }
}

// ---------------- MFMA window attention (R11 + vswz fix): one WAVE per (b,h) ---
// Q/K fragments direct from global; LDS = P[64][64] + VT[32][64] swizzled
// (12 KB/wave, 48 KB/block, 3 blk/CU); no __syncthreads (wave-private LDS).
// exp2-domain softmax with untransposed prescaled bias table (coalesced scalar
// loads). V swizzle u(d)=(d&7)^((d>>3)<<1): scatter-write 8-way -> 2-way.
__global__ __launch_bounds__(256) void attn_kernel(const bf16* __restrict__ qkv,
                                                   const float* __restrict__ cbias,
                                                   bf16* __restrict__ out) {
    __shared__ short lds[4 * 6144];
    const int t = threadIdx.x, lane = t & 63, wave = t >> 6;
    short* W = lds + wave * 6144;  // P @0 (4096), VT @4096 (2048)
    const int bh = blockIdx.x * 4 + wave;
    const int b = bh / 12, h = bh - b * 12;
    const int g = lane >> 4, c = lane & 15;
    const int w = b & 63;
    const size_t base = (size_t)b * 49 * 1152 + h * 32;
    const float scale2 = 0.17677669529663687f * 1.4426950408889634f;

    // ---- issue ALL global loads up front (one latency exposure)
    uint4 vr[3], vt4;
#pragma unroll
    for (int it = 0; it < 3; ++it) {
        int c4 = it * 64 + lane;
        int n = c4 >> 2, o = (c4 & 3) * 8;
        vr[it] = *(const uint4*)(qkv + base + (size_t)n * 1152 + 768 + o);
    }
    vt4 = *(const uint4*)(qkv + base + (size_t)48 * 1152 + 768 + (lane & 3) * 8);

    bf16x8 aq[4], bk[4];
#pragma unroll
    for (int mt = 0; mt < 4; ++mt) {
        int row = mt * 16 + c;
        row = row > 48 ? 48 : row;  // clamp: no OOB; garbage rows discarded later
        aq[mt] = *(const bf16x8*)(qkv + base + (size_t)row * 1152 + g * 8);
        bk[mt] = *(const bf16x8*)(qkv + base + (size_t)row * 1152 + 384 + g * 8);
    }

    // ---- zero VT (independent of loads)
#pragma unroll
    for (int z = 0; z < 4; ++z)
        *(uint4*)&W[4096 + (z * 64 + lane) * 8] = (uint4){0u, 0u, 0u, 0u};

    // ---- per-mt: QK^T -> fused bias (fma) -> exp2 -> sum -> P-pack -> ds_write
    const float* cb = cbias + ((size_t)((h << 6) | w) << 12);
    float inv[16];
#pragma unroll
    for (int mt = 0; mt < 4; ++mt) {
        f32x4 Sv[4];
#pragma unroll
        for (int nt = 0; nt < 4; ++nt)
            Sv[nt] = __builtin_amdgcn_mfma_f32_16x16x32_bf16(aq[mt], bk[nt],
                                                             (f32x4){0.f, 0.f, 0.f, 0.f}, 0, 0, 0);
        const int rowoff = (mt * 16 + g * 4) << 6;
#pragma unroll
        for (int nt = 0; nt < 4; ++nt) {
            int j = nt * 16 + c;
#pragma unroll
            for (int r = 0; r < 4; ++r)
                Sv[nt][r] = fmaf(Sv[nt][r], scale2, cb[rowoff + (r << 6) + j]);
        }
#pragma unroll
        for (int r = 0; r < 4; ++r) {
            float s = 0.f;
#pragma unroll
            for (int nt = 0; nt < 4; ++nt) {
                float e = exp2_fast(Sv[nt][r]);
                Sv[nt][r] = e;
                s += e;
            }
            s += __shfl_xor(s, 1);
            s += __shfl_xor(s, 2);
            s += __shfl_xor(s, 4);
            s += __shfl_xor(s, 8);
            inv[mt * 4 + r] = 1.f / s;
        }
        // P-pack: even lanes write nt 0-1, odd lanes nt 2-3 (b32 stores)
#pragma unroll
        for (int r = 0; r < 4; ++r) {
            const int i = mt * 16 + g * 4 + r;
            const int ix = (i & 7) << 3;
#pragma unroll
            for (int nt = 0; nt < 4; ++nt) {
                unsigned my = (unsigned)(unsigned short)bf16bits(Sv[nt][r]);
                unsigned oth = (unsigned)__builtin_amdgcn_mov_dpp((int)my, 0xB1, 0xF, 0xF, true);
                unsigned pair = (c & 1) ? (oth | (my << 16)) : (my | (oth << 16));
                const bool doit = (c & 1) ? (nt >= 2) : (nt < 2);
                if (doit) {
                    int j0 = nt * 16 + (c & ~1);
                    *(unsigned*)&W[i * 64 + (j0 ^ ix)] = pair;
                }
            }
        }
    }

    // ---- V transpose -> LDS (data arrived long ago), vswz banks
#pragma unroll
    for (int it = 0; it < 3; ++it) {
        int c4 = it * 64 + lane;
        int n = c4 >> 2, o = (c4 & 3) * 8;
        alignas(16) short tmp[8];
        *(uint4*)tmp = vr[it];
#pragma unroll
        for (int j = 0; j < 8; ++j) {
            int d = o + j;
            W[4096 + ((d * 64 + n) ^ vswz(d))] = tmp[j];
        }
    }
    if (lane < 4) {
        int o = lane * 8;
        alignas(16) short tmp[8];
        *(uint4*)tmp = vt4;
#pragma unroll
        for (int j = 0; j < 8; ++j) {
            int d = o + j;
            W[4096 + ((d * 64 + 48) ^ vswz(d))] = tmp[j];
        }
    }

    // ---- PV: O[i][d] = sum_j P[i][j] * VT[d][j]
    f32x4 O[4][2];
#pragma unroll
    for (int mt = 0; mt < 4; ++mt)
#pragma unroll
        for (int dt = 0; dt < 2; ++dt) O[mt][dt] = (f32x4){0.f, 0.f, 0.f, 0.f};
#pragma unroll
    for (int ks = 0; ks < 2; ++ks) {
        bf16x8 pa[4], vb2[2];
#pragma unroll
        for (int mt = 0; mt < 4; ++mt) {
            int i = mt * 16 + c;
            pa[mt] = *(const bf16x8*)&W[(i * 64 + ks * 32 + g * 8) ^ ((i & 7) << 3)];
        }
#pragma unroll
        for (int dt = 0; dt < 2; ++dt) {
            int d = dt * 16 + c;
            vb2[dt] = *(const bf16x8*)&W[4096 + ((d * 64 + ks * 32 + g * 8) ^ vswz(d))];
        }
#pragma unroll
        for (int mt = 0; mt < 4; ++mt)
#pragma unroll
            for (int dt = 0; dt < 2; ++dt)
                O[mt][dt] = __builtin_amdgcn_mfma_f32_16x16x32_bf16(pa[mt], vb2[dt],
                                                                    O[mt][dt], 0, 0, 0);
    }

    // ---- epilogue: normalize, DPP-pack pairs, b32 global stores (even lanes)
#pragma unroll
    for (int mt = 0; mt < 4; ++mt)
#pragma unroll
        for (int r = 0; r < 4; ++r) {
            int i = mt * 16 + g * 4 + r;
            const float iv = inv[mt * 4 + r];
            unsigned pair[2];
#pragma unroll
            for (int dt = 0; dt < 2; ++dt) {
                unsigned my = (unsigned)(unsigned short)bf16bits(O[mt][dt][r] * iv);
                unsigned oth = (unsigned)__builtin_amdgcn_mov_dpp((int)my, 0xB1, 0xF, 0xF, true);
                pair[dt] = my | (oth << 16);
            }
            if (i < 49 && !(c & 1)) {
                bf16* dst = out + ((size_t)(b * 49 + i)) * 384 + h * 32 + c;
                *(unsigned*)(dst) = pair[0];
                *(unsigned*)(dst + 16) = pair[1];
            }
        }
}

extern "C" void kernel_launch(void* const* d_in, const int* in_sizes, int n_in,
                              void* d_out, int out_size, void* d_ws, size_t ws_size,
                              hipStream_t stream) {
    (void)in_sizes; (void)n_in; (void)out_size; (void)ws_size;
    const float* x      = (const float*)d_in[0];
    const float* mask   = (const float*)d_in[1];
    const float* qkv_w  = (const float*)d_in[2];
    const float* qkv_b  = (const float*)d_in[3];
    const float* qa_w   = (const float*)d_in[4];
    const float* qb_w   = (const float*)d_in[5];
    const float* va_w   = (const float*)d_in[6];
    const float* vb_w   = (const float*)d_in[7];
    const float* rpb    = (const float*)d_in[8];
    const float* proj_w = (const float*)d_in[9];
    const float* proj_b = (const float*)d_in[10];

    char* ws = (char*)d_ws;
    // xb and attno share a region: xb dead after gemm1, attno written after.
    bf16* xb     = (bf16*)(ws);                    // 77,070,336 B
    bf16* attno  = (bf16*)(ws);                    // (same region, stream-ordered)
    bf16* wefft  = (bf16*)(ws + 77070336);         //    884,736 B
    bf16* projt  = (bf16*)(ws + 77955072);         //    294,912 B
    float* cbias = (float*)(ws + 78249984);        // 12,582,912 B
    bf16* qkv    = (bf16*)(ws + 90832896);         // 231,211,008 B (total ~322 MB)

    cvt_x_kernel<<<2048, 256, 0, stream>>>((const float4*)x, xb, 9633792);
    build_wefft_kernel<<<1728, 256, 0, stream>>>(qkv_w, qa_w, qb_w, va_w, vb_w, wefft);
    build_projt_kernel<<<576, 256, 0, stream>>>(proj_w, projt);
    build_cbias_kernel<<<12288, 256, 0, stream>>>(rpb, mask, cbias);
    // qkv[100352,1152] = xb @ wefft^T + qkv_b  -- R5 2-phase, split x2
    gemm_kernel<true><<<3528, 256, 0, stream>>>(xb, wefft, qkv_b, qkv, 1152, 384, 9, 3528);
    gemm_kernel<true><<<3528, 256, 0, stream>>>(xb + (size_t)50176 * 384, wefft, qkv_b,
                                                qkv + (size_t)50176 * 1152, 1152, 384, 9, 3528);
    attn_kernel<<<6144, 256, 0, stream>>>(qkv, cbias, attno);
    // out[100352,384] = attno @ projt^T + proj_b  (fp32)
    gemm_kernel<false><<<2352, 256, 0, stream>>>(attno, projt, proj_b, d_out, 384, 384, 3, 2352);
}

// Round 16
// 357.559 us; speedup vs baseline: 1.0581x; 1.0581x over previous
//
#include <hip/hip_runtime.h>
#include <hip/hip_bf16.h>

typedef __hip_bfloat16 bf16;
typedef float f32x4 __attribute__((ext_vector_type(4)));
typedef short bf16x8 __attribute__((ext_vector_type(8)));

static __device__ __forceinline__ void gload_lds16(const void* g, void* l) {
    __builtin_amdgcn_global_load_lds(
        (const __attribute__((address_space(1))) void*)g,
        (__attribute__((address_space(3))) void*)l, 16, 0, 0);
}

static __device__ __forceinline__ short bf16bits(float v) {
    bf16 tb = __float2bfloat16(v);
    return *reinterpret_cast<short*>(&tb);
}

static __device__ __forceinline__ float exp2_fast(float x) {
    float r;
    asm("v_exp_f32 %0, %1" : "=v"(r) : "v"(x));
    return r;
}

// ---------------- fp32 -> bf16 conversion (vectorized) ----------------
__global__ __launch_bounds__(256) void cvt_x_kernel(const float4* __restrict__ x,
                                                    bf16* __restrict__ xb, int n4) {
    int i = blockIdx.x * 256 + threadIdx.x;
    const int stride = gridDim.x * 256;
    for (; i < n4; i += stride) {
        float4 v = x[i];
        alignas(8) bf16 tmp[4];
        tmp[0] = __float2bfloat16(v.x);
        tmp[1] = __float2bfloat16(v.y);
        tmp[2] = __float2bfloat16(v.z);
        tmp[3] = __float2bfloat16(v.w);
        *reinterpret_cast<uint2*>(xb + 4l * i) = *reinterpret_cast<uint2*>(tmp);
    }
}

// ---------------- build W_eff^T (fold LoRA), bf16 ----------------
__global__ __launch_bounds__(256) void build_wefft_kernel(
    const float* __restrict__ qkv_w, const float* __restrict__ qa,
    const float* __restrict__ qb, const float* __restrict__ va,
    const float* __restrict__ vb, bf16* __restrict__ wt) {
    int idx = blockIdx.x * 256 + threadIdx.x;  // 1152*384 total
    int ncol = idx / 384;
    int k = idx - ncol * 384;
    float v = qkv_w[k * 1152 + ncol];
    if (ncol < 384) {
        float s = 0.f;
#pragma unroll
        for (int j = 0; j < 16; ++j) s += qa[k * 16 + j] * qb[j * 384 + ncol];
        v += s;
    } else if (ncol >= 768) {
        int nc = ncol - 768;
        float s = 0.f;
#pragma unroll
        for (int j = 0; j < 16; ++j) s += va[k * 16 + j] * vb[j * 384 + nc];
        v += s;
    }
    wt[(long)ncol * 384 + k] = __float2bfloat16(v);
}

// ---------------- transpose proj_w, bf16 ----------------
__global__ __launch_bounds__(256) void build_projt_kernel(const float* __restrict__ pw,
                                                          bf16* __restrict__ pt) {
    int idx = blockIdx.x * 256 + threadIdx.x;  // 384*384 total
    int ncol = idx / 384;
    int k = idx - ncol * 384;
    pt[(long)ncol * 384 + k] = __float2bfloat16(pw[k * 384 + ncol]);
}

// ------- padded+prescaled bias: cbias[h][w][i*64+j], value*(log2 e) -------
// j>=49 -> -1e30 (exp2 -> 0); i in [49,64) pad rows -> 0 (rows discarded).
__global__ __launch_bounds__(256) void build_cbias_kernel(const float* __restrict__ rpb_table,
                                                          const float* __restrict__ mask,
                                                          float* __restrict__ cbias) {
    int idx = blockIdx.x * 256 + threadIdx.x;  // 12*64*64*64 = 12288*256
    int h = idx >> 18;
    int w = (idx >> 12) & 63;
    int ij = idx & 4095;
    int i = ij >> 6, j = ij & 63;
    float v;
    if (j < 49) {
        if (i < 49) {
            int yi = i / 7, xi = i - yi * 7;
            int yj = j / 7, xj = j - yj * 7;
            int rel = (yi - yj + 6) * 13 + (xi - xj + 6);
            v = (rpb_table[rel * 12 + h] + mask[w * 2401 + i * 49 + j]) * 1.4426950408889634f;
        } else {
            v = 0.f;
        }
    } else {
        v = -1e30f;
    }
    cbias[idx] = v;
}

// ---------------- GEMM (R5 known-good): C[M,N] = A[M,K] @ BT[N,K]^T + bias ----
template <bool OUT_BF16>
__global__ __launch_bounds__(256) void gemm_kernel(const bf16* __restrict__ A,
                                                   const bf16* __restrict__ BT,
                                                   const float* __restrict__ bias,
                                                   void* __restrict__ Cout,
                                                   int N, int K, int nxb, int nwg) {
    __shared__ short Al[128 * 64];
    __shared__ short Bl[128 * 64];
    const int t = threadIdx.x;
    const int lane = t & 63;
    const int wave = t >> 6;
    const int wr = wave >> 1;
    const int wc = wave & 1;
    const int g = lane >> 4, c = lane & 15;

    const int q8 = nwg >> 3;
    const int wgid = (blockIdx.x & 7) * q8 + (blockIdx.x >> 3);
    const int by = wgid / nxb;
    const int bx = wgid - by * nxb;
    const long rowBase = (long)by * 128;
    const long colBase = (long)bx * 128;

    f32x4 acc[4][4];
#pragma unroll
    for (int m = 0; m < 4; ++m)
#pragma unroll
        for (int n = 0; n < 4; ++n) acc[m][n] = (f32x4){0.f, 0.f, 0.f, 0.f};

    for (int k0 = 0; k0 < K; k0 += 64) {
        __syncthreads();
#pragma unroll
        for (int it = 0; it < 4; ++it) {
            int chunk = it * 256 + t;
            int row = chunk >> 3;
            int blk = lane & 7;
            gload_lds16(A + (size_t)(rowBase + row) * K + k0 + ((blk ^ (row & 7)) * 8),
                        &Al[(it * 256 + wave * 64) * 8]);
            gload_lds16(BT + (size_t)(colBase + row) * K + k0 + ((blk ^ (row & 7)) * 8),
                        &Bl[(it * 256 + wave * 64) * 8]);
        }
        asm volatile("s_waitcnt vmcnt(0)" ::: "memory");
        __syncthreads();

#pragma unroll
        for (int ks = 0; ks < 2; ++ks) {
            bf16x8 af[4], bfr[4];
#pragma unroll
            for (int m = 0; m < 4; ++m) {
                int row = wr * 64 + m * 16 + c;
                af[m] = *(const bf16x8*)&Al[row * 64 + (((ks * 4 + g) ^ (c & 7)) * 8)];
            }
#pragma unroll
            for (int n = 0; n < 4; ++n) {
                int row = wc * 64 + n * 16 + c;
                bfr[n] = *(const bf16x8*)&Bl[row * 64 + (((ks * 4 + g) ^ (c & 7)) * 8)];
            }
#pragma unroll
            for (int m = 0; m < 4; ++m)
#pragma unroll
                for (int n = 0; n < 4; ++n)
                    acc[m][n] = __builtin_amdgcn_mfma_f32_16x16x32_bf16(af[m], bfr[n],
                                                                        acc[m][n], 0, 0, 0);
        }
    }

    const int crow0 = wr * 64 + g * 4;
    const long ccol0 = colBase + wc * 64 + c;
#pragma unroll
    for (int m = 0; m < 4; ++m) {
#pragma unroll
        for (int n = 0; n < 4; ++n) {
            const long col = ccol0 + n * 16;
            const float bv = bias[col];
#pragma unroll
            for (int r = 0; r < 4; ++r) {
                const long row = rowBase + crow0 + m * 16 + r;
                float v = acc[m][n][r] + bv;
                if (OUT_BF16)
                    ((bf16*)Cout)[row * N + col] = __float2bfloat16(v);
                else
                    ((float*)Cout)[row * N + col] = v;
            }
        }
    }
}

// ---------------- MFMA window attention (R11 exact): one WAVE per (b, h) ------
// Q/K fragments direct from global; LDS = P[64][64] + VT[32][64] XOR-swizzled
// ((d&7)<<3); 12 KB/wave, 48 KB/block, 3 blk/CU; no __syncthreads (wave-private
// LDS). exp2-domain softmax: t = fma(S, scale*log2e, cb[i*64+j]), coalesced
// untransposed prescaled bias table; shuffle rowsum; DPP-packed b32 stores.
__global__ __launch_bounds__(256) void attn_kernel(const bf16* __restrict__ qkv,
                                                   const float* __restrict__ cbias,
                                                   bf16* __restrict__ out) {
    __shared__ short lds[4 * 6144];
    const int t = threadIdx.x, lane = t & 63, wave = t >> 6;
    short* W = lds + wave * 6144;  // P @0 (4096), VT @4096 (2048)
    const int bh = blockIdx.x * 4 + wave;
    const int b = bh / 12, h = bh - b * 12;
    const int g = lane >> 4, c = lane & 15;
    const int w = b & 63;
    const size_t base = (size_t)b * 49 * 1152 + h * 32;
    const float scale2 = 0.17677669529663687f * 1.4426950408889634f;

    // ---- issue ALL global loads up front (one latency exposure)
    uint4 vr[3], vt4;
#pragma unroll
    for (int it = 0; it < 3; ++it) {
        int c4 = it * 64 + lane;
        int n = c4 >> 2, o = (c4 & 3) * 8;
        vr[it] = *(const uint4*)(qkv + base + (size_t)n * 1152 + 768 + o);
    }
    vt4 = *(const uint4*)(qkv + base + (size_t)48 * 1152 + 768 + (lane & 3) * 8);

    bf16x8 aq[4], bk[4];
#pragma unroll
    for (int mt = 0; mt < 4; ++mt) {
        int row = mt * 16 + c;
        row = row > 48 ? 48 : row;  // clamp: no OOB; garbage rows discarded later
        aq[mt] = *(const bf16x8*)(qkv + base + (size_t)row * 1152 + g * 8);
        bk[mt] = *(const bf16x8*)(qkv + base + (size_t)row * 1152 + 384 + g * 8);
    }

    // ---- zero VT (independent of loads)
#pragma unroll
    for (int z = 0; z < 4; ++z)
        *(uint4*)&W[4096 + (z * 64 + lane) * 8] = (uint4){0u, 0u, 0u, 0u};

    // ---- per-mt: QK^T -> fused bias (fma) -> exp2 -> sum -> P-pack -> ds_write
    const float* cb = cbias + ((size_t)((h << 6) | w) << 12);
    float inv[16];
#pragma unroll
    for (int mt = 0; mt < 4; ++mt) {
        f32x4 Sv[4];
#pragma unroll
        for (int nt = 0; nt < 4; ++nt)
            Sv[nt] = __builtin_amdgcn_mfma_f32_16x16x32_bf16(aq[mt], bk[nt],
                                                             (f32x4){0.f, 0.f, 0.f, 0.f}, 0, 0, 0);
        const int rowoff = (mt * 16 + g * 4) << 6;
#pragma unroll
        for (int nt = 0; nt < 4; ++nt) {
            int j = nt * 16 + c;
#pragma unroll
            for (int r = 0; r < 4; ++r)
                Sv[nt][r] = fmaf(Sv[nt][r], scale2, cb[rowoff + (r << 6) + j]);
        }
#pragma unroll
        for (int r = 0; r < 4; ++r) {
            float s = 0.f;
#pragma unroll
            for (int nt = 0; nt < 4; ++nt) {
                float e = exp2_fast(Sv[nt][r]);
                Sv[nt][r] = e;
                s += e;
            }
            s += __shfl_xor(s, 1);
            s += __shfl_xor(s, 2);
            s += __shfl_xor(s, 4);
            s += __shfl_xor(s, 8);
            inv[mt * 4 + r] = 1.f / s;
        }
        // P-pack: even lanes write nt 0-1, odd lanes nt 2-3 (b32 stores)
#pragma unroll
        for (int r = 0; r < 4; ++r) {
            const int i = mt * 16 + g * 4 + r;
            const int ix = (i & 7) << 3;
#pragma unroll
            for (int nt = 0; nt < 4; ++nt) {
                unsigned my = (unsigned)(unsigned short)bf16bits(Sv[nt][r]);
                unsigned oth = (unsigned)__builtin_amdgcn_mov_dpp((int)my, 0xB1, 0xF, 0xF, true);
                unsigned pair = (c & 1) ? (oth | (my << 16)) : (my | (oth << 16));
                const bool doit = (c & 1) ? (nt >= 2) : (nt < 2);
                if (doit) {
                    int j0 = nt * 16 + (c & ~1);
                    *(unsigned*)&W[i * 64 + (j0 ^ ix)] = pair;
                }
            }
        }
    }

    // ---- V transpose -> LDS (data arrived long ago)
#pragma unroll
    for (int it = 0; it < 3; ++it) {
        int c4 = it * 64 + lane;
        int n = c4 >> 2, o = (c4 & 3) * 8;
        alignas(16) short tmp[8];
        *(uint4*)tmp = vr[it];
#pragma unroll
        for (int j = 0; j < 8; ++j) {
            int d = o + j;
            W[4096 + ((d * 64 + n) ^ ((d & 7) << 3))] = tmp[j];
        }
    }
    if (lane < 4) {
        int o = lane * 8;
        alignas(16) short tmp[8];
        *(uint4*)tmp = vt4;
#pragma unroll
        for (int j = 0; j < 8; ++j) {
            int d = o + j;
            W[4096 + ((d * 64 + 48) ^ ((d & 7) << 3))] = tmp[j];
        }
    }

    // ---- PV: O[i][d] = sum_j P[i][j] * VT[d][j]
    f32x4 O[4][2];
#pragma unroll
    for (int mt = 0; mt < 4; ++mt)
#pragma unroll
        for (int dt = 0; dt < 2; ++dt) O[mt][dt] = (f32x4){0.f, 0.f, 0.f, 0.f};
#pragma unroll
    for (int ks = 0; ks < 2; ++ks) {
        bf16x8 pa[4], vb2[2];
#pragma unroll
        for (int mt = 0; mt < 4; ++mt) {
            int i = mt * 16 + c;
            pa[mt] = *(const bf16x8*)&W[(i * 64 + ks * 32 + g * 8) ^ ((i & 7) << 3)];
        }
#pragma unroll
        for (int dt = 0; dt < 2; ++dt) {
            int d = dt * 16 + c;
            vb2[dt] = *(const bf16x8*)&W[4096 + ((d * 64 + ks * 32 + g * 8) ^ ((d & 7) << 3))];
        }
#pragma unroll
        for (int mt = 0; mt < 4; ++mt)
#pragma unroll
            for (int dt = 0; dt < 2; ++dt)
                O[mt][dt] = __builtin_amdgcn_mfma_f32_16x16x32_bf16(pa[mt], vb2[dt],
                                                                    O[mt][dt], 0, 0, 0);
    }

    // ---- epilogue: normalize, DPP-pack pairs, b32 global stores (even lanes)
#pragma unroll
    for (int mt = 0; mt < 4; ++mt)
#pragma unroll
        for (int r = 0; r < 4; ++r) {
            int i = mt * 16 + g * 4 + r;
            const float iv = inv[mt * 4 + r];
            unsigned pair[2];
#pragma unroll
            for (int dt = 0; dt < 2; ++dt) {
                unsigned my = (unsigned)(unsigned short)bf16bits(O[mt][dt][r] * iv);
                unsigned oth = (unsigned)__builtin_amdgcn_mov_dpp((int)my, 0xB1, 0xF, 0xF, true);
                pair[dt] = my | (oth << 16);
            }
            if (i < 49 && !(c & 1)) {
                bf16* dst = out + ((size_t)(b * 49 + i)) * 384 + h * 32 + c;
                *(unsigned*)(dst) = pair[0];
                *(unsigned*)(dst + 16) = pair[1];
            }
        }
}

extern "C" void kernel_launch(void* const* d_in, const int* in_sizes, int n_in,
                              void* d_out, int out_size, void* d_ws, size_t ws_size,
                              hipStream_t stream) {
    (void)in_sizes; (void)n_in; (void)out_size; (void)ws_size;
    const float* x      = (const float*)d_in[0];
    const float* mask   = (const float*)d_in[1];
    const float* qkv_w  = (const float*)d_in[2];
    const float* qkv_b  = (const float*)d_in[3];
    const float* qa_w   = (const float*)d_in[4];
    const float* qb_w   = (const float*)d_in[5];
    const float* va_w   = (const float*)d_in[6];
    const float* vb_w   = (const float*)d_in[7];
    const float* rpb    = (const float*)d_in[8];
    const float* proj_w = (const float*)d_in[9];
    const float* proj_b = (const float*)d_in[10];

    char* ws = (char*)d_ws;
    // xb and attno share a region: xb dead after gemm1, attno written after.
    bf16* xb     = (bf16*)(ws);                    // 77,070,336 B
    bf16* attno  = (bf16*)(ws);                    // (same region, stream-ordered)
    bf16* wefft  = (bf16*)(ws + 77070336);         //    884,736 B
    bf16* projt  = (bf16*)(ws + 77955072);         //    294,912 B
    float* cbias = (float*)(ws + 78249984);        // 12,582,912 B
    bf16* qkv    = (bf16*)(ws + 90832896);         // 231,211,008 B (total ~322 MB)

    cvt_x_kernel<<<2048, 256, 0, stream>>>((const float4*)x, xb, 9633792);
    build_wefft_kernel<<<1728, 256, 0, stream>>>(qkv_w, qa_w, qb_w, va_w, vb_w, wefft);
    build_projt_kernel<<<576, 256, 0, stream>>>(proj_w, projt);
    build_cbias_kernel<<<12288, 256, 0, stream>>>(rpb, mask, cbias);
    // qkv[100352,1152] = xb @ wefft^T + qkv_b  (single dispatch, best balance)
    gemm_kernel<true><<<7056, 256, 0, stream>>>(xb, wefft, qkv_b, qkv, 1152, 384, 9, 7056);
    attn_kernel<<<6144, 256, 0, stream>>>(qkv, cbias, attno);
    // out[100352,384] = attno @ projt^T + proj_b  (fp32)
    gemm_kernel<false><<<2352, 256, 0, stream>>>(attno, projt, proj_b, d_out, 384, 384, 3, 2352);
}